// Round 1
// baseline (460.589 us; speedup 1.0000x reference)
//
#include <hip/hip_runtime.h>

typedef __attribute__((ext_vector_type(8))) short short8;
typedef __attribute__((ext_vector_type(4))) float f32x4;

#define CIN   128
#define COUT  256
#define H     112
#define W     112
#define OH    110
#define OW    110
#define KHW   9
#define TH    16
#define TW    16
#define IH    18
#define IW    18
#define NPIX  (IH*IW)            // 324
#define X_BYTES (NPIX*CIN*2)     // 82944
#define W_BYTES (COUT*CIN*2)     // 65536

__device__ __forceinline__ short f2b(float f) {
  unsigned u = __builtin_bit_cast(unsigned, f);
  unsigned r = (u + 0x7FFFu + ((u >> 16) & 1u)) >> 16;  // RNE
  return (short)r;
}

// x tile LDS layout: [pixel p (324)][cin group G (16)] of 16B slots, slot
// index swizzled: off = p*256 + ((G ^ (p&15))<<4) + (cin&7)*2.
// w tile LDS layout: [cout (256)][G (16)]: off = cout*256 + ((G ^ (cout&15))<<4).
// Swizzle applied identically on write and read -> correct by construction,
// and spreads the stride-256B ds_read_b128 pattern across all bank granules.

template<bool USE_WT>
__global__ __launch_bounds__(512, 2)
void conv_main(const float* __restrict__ x, const float* __restrict__ wgt,
               const short* __restrict__ wt, float* __restrict__ out) {
  __shared__ __align__(16) char smem[X_BYTES + W_BYTES];
  char* sx = smem;
  char* sw = smem + X_BYTES;

  const int tid = threadIdx.x;
  const int b   = blockIdx.y;
  const int t_h = blockIdx.x / 7;
  const int t_w = blockIdx.x - t_h * 7;
  const int h0 = t_h * TH, w0 = t_w * TW;

  // ---- stage x halo tile: 18x18 pixels x 128 cin, f32 -> bf16 ----
  const float* xb = x + (size_t)b * CIN * (H*W);
  for (int u = tid; u < NPIX * (CIN/8); u += 512) {   // 5184 units of 8 cin
    int G = u / NPIX;             // cin group 0..15
    int p = u - G * NPIX;         // pixel 0..323
    int iy = p / IW, ix = p - iy * IW;
    int gy = h0 + iy, gx = w0 + ix;
    short8 v = {0,0,0,0,0,0,0,0};
    if (gy < H && gx < W) {
      const float* s = xb + (size_t)(G*8) * (H*W) + gy * W + gx;
      #pragma unroll
      for (int j = 0; j < 8; ++j) v[j] = f2b(s[j * (H*W)]);
    }
    *(short8*)(sx + p*256 + ((G ^ (p & 15)) << 4)) = v;
  }

  const int lane = tid & 63;
  const int wid  = tid >> 6;
  const int wm = wid >> 2;        // 0..1  -> couts [wm*128, +128)
  const int wn = wid & 3;         // 0..3  -> tile rows ty in [wn*4, +4)
  const int l15 = lane & 15;
  const int lg  = lane >> 4;      // 0..3

  f32x4 acc[8][4] = {};

  for (int khw = 0; khw < 9; ++khw) {
    __syncthreads();              // protect w_lds (and x tile on first iter)
    if (USE_WT) {
      const short* src = wt + (size_t)khw * (COUT*CIN);
      for (int u = tid; u < COUT * (CIN/8); u += 512) {  // 4096 units
        int cout = u >> 4, G = u & 15;
        short8 v = *(const short8*)(src + u * 8);
        *(short8*)(sw + cout*256 + ((G ^ (cout & 15)) << 4)) = v;
      }
    } else {
      for (int i = tid; i < COUT*CIN; i += 512) {
        int cout = i >> 7, cin = i & 127;
        float f = wgt[cout*(CIN*KHW) + cin*KHW + khw];
        int G = cin >> 3;
        *(short*)(sw + cout*256 + ((G ^ (cout & 15)) << 4) + (cin & 7)*2) = f2b(f);
      }
    }
    __syncthreads();

    const int kh = khw / 3, kw = khw - (khw/3)*3;
    #pragma unroll
    for (int s = 0; s < 4; ++s) {             // four K=32 steps over 128 cin
      const int G = s*4 + lg;
      short8 a[8];
      #pragma unroll
      for (int mi = 0; mi < 8; ++mi) {
        int cout = wm*128 + mi*16 + l15;
        a[mi] = *(const short8*)(sw + cout*256 + ((G ^ l15) << 4));
      }
      #pragma unroll
      for (int ni = 0; ni < 4; ++ni) {
        int ty = wn*4 + ni;
        int p = (ty + kh) * IW + (l15 + kw);
        short8 bf = *(const short8*)(sx + p*256 + ((G ^ (p & 15)) << 4));
        #pragma unroll
        for (int mi = 0; mi < 8; ++mi)
          acc[mi][ni] = __builtin_amdgcn_mfma_f32_16x16x32_bf16(a[mi], bf, acc[mi][ni], 0, 0, 0);
      }
    }
  }

  // ---- epilogue: C layout col=lane&15, row=4*(lane>>4)+r (m89) ----
  float* ob = out + (size_t)b * COUT * (OH*OW);
  #pragma unroll
  for (int ni = 0; ni < 4; ++ni) {
    int ty = wn*4 + ni;
    int oh = h0 + ty;
    int ow = w0 + l15;
    if (oh < OH && ow < OW) {
      #pragma unroll
      for (int mi = 0; mi < 8; ++mi) {
        #pragma unroll
        for (int r = 0; r < 4; ++r) {
          int cout = wm*128 + mi*16 + lg*4 + r;
          ob[cout*(OH*OW) + oh*OW + ow] = acc[mi][ni][r];
        }
      }
    }
  }
}

// one-time weight transpose+cvt: wt[khw][cout][cin] bf16
__global__ void wprep(const float* __restrict__ wgt, short* __restrict__ wt) {
  int idx = blockIdx.x * 256 + threadIdx.x;
  if (idx >= KHW*COUT*CIN) return;
  int khw  = idx / (COUT*CIN);
  int rem  = idx - khw*(COUT*CIN);
  int cout = rem >> 7, cin = rem & 127;
  wt[idx] = f2b(wgt[cout*(CIN*KHW) + cin*KHW + khw]);
}

extern "C" void kernel_launch(void* const* d_in, const int* in_sizes, int n_in,
                              void* d_out, int out_size, void* d_ws, size_t ws_size,
                              hipStream_t stream) {
  const float* x   = (const float*)d_in[0];
  const float* wgt = (const float*)d_in[1];
  float* out = (float*)d_out;
  const size_t wt_bytes = (size_t)(KHW*COUT*CIN) * sizeof(short);
  dim3 grid(49, 32);   // 7x7 spatial tiles x 32 batches
  if (ws_size >= wt_bytes) {
    short* wt = (short*)d_ws;
    wprep<<<(KHW*COUT*CIN + 255)/256, 256, 0, stream>>>(wgt, wt);
    conv_main<true><<<grid, 512, 0, stream>>>(x, wgt, wt, out);
  } else {
    conv_main<false><<<grid, 512, 0, stream>>>(x, wgt, nullptr, out);
  }
}